// Round 1
// baseline (31580.466 us; speedup 1.0000x reference)
//
#include <hip/hip_runtime.h>
#include <hip/hip_cooperative_groups.h>

namespace cg = cooperative_groups;

#define B_   64
#define T_   512
#define DI_  512
#define H_   1024
#define G4H  4096

__device__ __forceinline__ float sigm(float x) {
    return 1.0f / (1.0f + __expf(-x));
}
__device__ __forceinline__ float tanh_fast(float x) {
    return 2.0f / (1.0f + __expf(-2.0f * x)) - 1.0f;
}

// Pack Whh into per-block slices: Wpk[bid][k][n] = Whh[(n>>2)*1024 + bid*4 + (n&3)][k]
// Block bid owns h-columns j0..j0+3 (j0 = bid*4) -> 16 gate rows (4 gates x 4 cols).
__global__ __launch_bounds__(256) void pack_whh(
    const float* __restrict__ Whh, float* __restrict__ Wpk)
{
    const int bid = blockIdx.x;
    const int j0  = bid * 4;
    const int tid = threadIdx.x;
    const int n   = tid >> 4;      // 0..15
    const int lo  = tid & 15;      // 0..15
    const int row = (n >> 2) * H_ + j0 + (n & 3);
    const float* src = Whh + (size_t)row * H_;
    float* dst = Wpk + (size_t)bid * 16384 + n;
#pragma unroll
    for (int u = 0; u < 16; ++u) {
        const int k = u * 64 + lo * 4;
        const float4 v = *(const float4*)(src + k);
        dst[(size_t)(k + 0) * 16] = v.x;
        dst[(size_t)(k + 1) * 16] = v.y;
        dst[(size_t)(k + 2) * 16] = v.z;
        dst[(size_t)(k + 3) * 16] = v.w;
    }
}

// xp[tl][b][n] = X[b][t0+tl][:] . Wih[n][:] + (bih[n]+bhh[n])   (unchanged)
__global__ __launch_bounds__(256) void xproj_gemm(
    const float* __restrict__ X, const float* __restrict__ Wih,
    const float* __restrict__ bih, const float* __restrict__ bhh,
    float* __restrict__ xp, int t0)
{
    __shared__ float As[16][64];   // [k][b]
    __shared__ float Bs[16][64];   // [k][n]
    const int tl = blockIdx.y;
    const int n0 = blockIdx.x * 64;
    const int t  = t0 + tl;
    const int tid = threadIdx.x;
    const int ab = tid >> 2;
    const int ak = (tid & 3) * 4;
    const int wn = tid >> 2;
    const int wk = (tid & 3) * 4;
    const int by = tid >> 4;
    const int nx = tid & 15;

    const float* Ap = X + ((size_t)ab * T_ + t) * DI_ + ak;
    const float* Bp = Wih + (size_t)(n0 + wn) * DI_ + wk;

    float acc[4][4] = {};

    for (int k0 = 0; k0 < DI_; k0 += 16) {
        const float4 av = *(const float4*)(Ap + k0);
        const float4 bv = *(const float4*)(Bp + k0);
        __syncthreads();
        As[ak + 0][ab] = av.x; As[ak + 1][ab] = av.y;
        As[ak + 2][ab] = av.z; As[ak + 3][ab] = av.w;
        Bs[wk + 0][wn] = bv.x; Bs[wk + 1][wn] = bv.y;
        Bs[wk + 2][wn] = bv.z; Bs[wk + 3][wn] = bv.w;
        __syncthreads();
#pragma unroll
        for (int k = 0; k < 16; ++k) {
            const float4 a4 = *(const float4*)&As[k][by * 4];
            const float4 b4 = *(const float4*)&Bs[k][nx * 4];
            const float ar[4] = {a4.x, a4.y, a4.z, a4.w};
            const float br[4] = {b4.x, b4.y, b4.z, b4.w};
#pragma unroll
            for (int i = 0; i < 4; ++i)
#pragma unroll
                for (int j = 0; j < 4; ++j)
                    acc[i][j] = fmaf(ar[i], br[j], acc[i][j]);
        }
    }

    const int nb = n0 + nx * 4;
    const float4 b1 = *(const float4*)(bih + nb);
    const float4 b2 = *(const float4*)(bhh + nb);
    const float4 bb4 = {b1.x + b2.x, b1.y + b2.y, b1.z + b2.z, b1.w + b2.w};
#pragma unroll
    for (int i = 0; i < 4; ++i) {
        const int b = by * 4 + i;
        float4 v;
        v.x = acc[i][0] + bb4.x;
        v.y = acc[i][1] + bb4.y;
        v.z = acc[i][2] + bb4.z;
        v.w = acc[i][3] + bb4.w;
        *(float4*)(xp + ((size_t)tl * B_ + b) * G4H + nb) = v;
    }
}

// Persistent cooperative recurrence kernel.
// Grid 256 blocks (1/CU), 512 threads (8 waves). Block bid owns h-cols j0..j0+3.
// Per step: gates(64b x 16n) = xp + h . Whh^T(slice); pointwise; update hT/cS; write hs/cs.
// hT is h transposed: hT[k][b] (k=0..1023, b=0..63) so k-tiles are contiguous 16 KB.
__global__ __launch_bounds__(512, 2) void lstm_recur(
    const float* __restrict__ Wpk, const float* __restrict__ xp,
    float* __restrict__ hT, float* __restrict__ cS,
    float* __restrict__ hs, float* __restrict__ cs,
    int t0, int clen)
{
    __shared__ float Hs[2][4096];      // two 64k x 64b h tiles
    __shared__ float Wt[2][1280];      // two 64k x 16n W tiles, row stride 20 (pad)
    __shared__ float gate[64 * 21];    // [b][n], stride 21 to spread atomics
    __shared__ float hloc[256];        // [q][b] h_new staging for transposed write

    const int tid = threadIdx.x;
    const int bid = blockIdx.x;
    const int j0  = bid * 4;
    const float* Wb = Wpk + (size_t)bid * 16384;

    const int wv = tid >> 6;           // wave 0..7 -> k-subrange within tile
    const int ln = tid & 63;
    const int b4 = ln >> 2;            // 0..15 -> batches b4*4..+3
    const int n4 = ln & 3;             // 0..3  -> gate cols n4*4..+3

    cg::grid_group grid = cg::this_grid();

    for (int tl = 0; tl < clen; ++tl) {
        const int t = t0 + tl;

        // ---- stage tile 0 (h rows 0..63 + W rows 0..63); init gates with xp ----
        {
            const float4 a0 = *(const float4*)(hT + tid * 4);
            const float4 a1 = *(const float4*)(hT + 2048 + tid * 4);
            *(float4*)(&Hs[0][tid * 4])        = a0;
            *(float4*)(&Hs[0][2048 + tid * 4]) = a1;
        }
        if (tid < 256) {
            const float4 w = *(const float4*)(Wb + tid * 4);
            *(float4*)(&Wt[0][(tid >> 2) * 20 + (tid & 3) * 4]) = w;
        } else {
            const int q = tid - 256;           // 0..255
            const int b = q >> 2, g = q & 3;
            const float4 v = *(const float4*)(xp + ((size_t)tl * B_ + b) * G4H + g * H_ + j0);
            float* gp = gate + b * 21 + g * 4;
            gp[0] = v.x; gp[1] = v.y; gp[2] = v.z; gp[3] = v.w;
        }
        __syncthreads();

        // ---- K loop: 16 tiles of 64 k, double-buffered; wave wv covers k = wv*8..wv*8+7 ----
        float acc[4][4] = {};
        for (int kt = 0; kt < 16; ++kt) {
            const int buf = kt & 1;
            float4 r0, r1, w4;
            if (kt < 15) {
                const float* hsrc = hT + (kt + 1) * 4096;
                r0 = *(const float4*)(hsrc + tid * 4);
                r1 = *(const float4*)(hsrc + 2048 + tid * 4);
                if (tid < 256)
                    w4 = *(const float4*)(Wb + (size_t)(kt + 1) * 1024 + tid * 4);
            }
            const float* Hb   = &Hs[buf][0];
            const float* Wrow = &Wt[buf][0];
#pragma unroll
            for (int kk = 0; kk < 8; ++kk) {
                const int k = wv * 8 + kk;
                const float4 hv = *(const float4*)(Hb + k * 64 + b4 * 4);
                const float4 wq = *(const float4*)(Wrow + k * 20 + n4 * 4);
                const float hr[4] = {hv.x, hv.y, hv.z, hv.w};
                const float wr[4] = {wq.x, wq.y, wq.z, wq.w};
#pragma unroll
                for (int i = 0; i < 4; ++i)
#pragma unroll
                    for (int j = 0; j < 4; ++j)
                        acc[i][j] = fmaf(hr[i], wr[j], acc[i][j]);
            }
            if (kt < 15) {
                *(float4*)(&Hs[buf ^ 1][tid * 4])        = r0;
                *(float4*)(&Hs[buf ^ 1][2048 + tid * 4]) = r1;
                if (tid < 256)
                    *(float4*)(&Wt[buf ^ 1][(tid >> 2) * 20 + (tid & 3) * 4]) = w4;
                __syncthreads();
            }
        }

        // ---- cross-wave reduce into gates ----
#pragma unroll
        for (int i = 0; i < 4; ++i)
#pragma unroll
            for (int j = 0; j < 4; ++j)
                atomicAdd(&gate[(b4 * 4 + i) * 21 + n4 * 4 + j], acc[i][j]);
        __syncthreads();

        // ---- pointwise: gates -> c,h; write cS, hs, cs; stage h_new for hT ----
        if (tid < 64) {
            const int b = tid;
            const float* gp = gate + b * 21;
            const float4 cv = *(const float4*)(cS + (size_t)b * H_ + j0);
            const float cc[4] = {cv.x, cv.y, cv.z, cv.w};
            float cn[4], hn[4];
#pragma unroll
            for (int q = 0; q < 4; ++q) {
                const float ig = sigm(gp[q]);
                const float fg = sigm(gp[4 + q]);
                const float gg = tanh_fast(gp[8 + q]);
                const float og = sigm(gp[12 + q]);
                const float c2 = fmaf(fg, cc[q], ig * gg);
                cn[q] = c2;
                hn[q] = og * tanh_fast(c2);
            }
            const float4 c4 = {cn[0], cn[1], cn[2], cn[3]};
            const float4 h4 = {hn[0], hn[1], hn[2], hn[3]};
            *(float4*)(cS + (size_t)b * H_ + j0) = c4;
            const size_t o = ((size_t)b * T_ + t) * H_ + j0;
            *(float4*)(hs + o) = h4;
            *(float4*)(cs + o) = c4;
            hloc[0 * 64 + b] = hn[0];
            hloc[1 * 64 + b] = hn[1];
            hloc[2 * 64 + b] = hn[2];
            hloc[3 * 64 + b] = hn[3];
        }
        __syncthreads();
        if (tid < 64) {
            const int q = tid >> 4, x = tid & 15;
            *(float4*)(hT + (j0 + q) * 64 + x * 4) = *(const float4*)(hloc + q * 64 + x * 4);
        }
        grid.sync();
    }
}

__global__ __launch_bounds__(256) void gather_last(
    const float* __restrict__ hs, const float* __restrict__ cs,
    const int* __restrict__ length,
    float* __restrict__ hl, float* __restrict__ cl)
{
    const int i = blockIdx.x * 256 + threadIdx.x;   // B*H total
    const int b = i >> 10;
    const int j = i & 1023;
    const int tt = length[b] - 1;
    const size_t src = ((size_t)b * T_ + tt) * H_ + j;
    hl[i] = hs[src];
    cl[i] = cs[src];
}

extern "C" void kernel_launch(void* const* d_in, const int* in_sizes, int n_in,
                              void* d_out, int out_size, void* d_ws, size_t ws_size,
                              hipStream_t stream)
{
    const float* X   = (const float*)d_in[0];
    const float* Wih = (const float*)d_in[1];
    const float* Whh = (const float*)d_in[2];
    const float* bih = (const float*)d_in[3];
    const float* bhh = (const float*)d_in[4];
    const int*   len = (const int*)d_in[5];

    float* out = (float*)d_out;
    float* hs = out;
    float* cs = hs + (size_t)B_ * T_ * H_;
    float* hl = cs + (size_t)B_ * T_ * H_;
    float* cl = hl + (size_t)B_ * H_;

    // ws layout: hT (1024x64) | cS (64x1024) | Wpk (1024x4096) | xp chunk
    float* hT  = (float*)d_ws;
    float* cS  = hT + 65536;
    float* Wpk = cS + 65536;
    float* xp  = Wpk + (size_t)H_ * G4H;

    const size_t fixed_bytes = ((size_t)131072 + (size_t)H_ * G4H) * sizeof(float);
    const size_t per_t = (size_t)B_ * G4H * sizeof(float);   // 1 MiB per timestep

    int Tc = 1;
    if (ws_size > fixed_bytes + per_t) {
        size_t m = (ws_size - fixed_bytes) / per_t;
        Tc = (int)(m > (size_t)T_ ? (size_t)T_ : m);
    }

    hipMemsetAsync(hT, 0, (size_t)131072 * sizeof(float), stream);   // hT + cS
    pack_whh<<<256, 256, 0, stream>>>(Whh, Wpk);

    for (int t0 = 0; t0 < T_; t0 += Tc) {
        const int clen = (T_ - t0 < Tc) ? (T_ - t0) : Tc;
        xproj_gemm<<<dim3(G4H / 64, clen), 256, 0, stream>>>(X, Wih, bih, bhh, xp, t0);
        int t0a = t0, cla = clen;
        void* args[] = {(void*)&Wpk, (void*)&xp, (void*)&hT, (void*)&cS,
                        (void*)&hs, (void*)&cs, (void*)&t0a, (void*)&cla};
        hipLaunchCooperativeKernel((const void*)lstm_recur, dim3(256), dim3(512),
                                   args, 0, stream);
    }

    gather_last<<<(B_ * H_) / 256, 256, 0, stream>>>(hs, cs, len, hl, cl);
}

// Round 2
// 29255.850 us; speedup vs baseline: 1.0795x; 1.0795x over previous
//
#include <hip/hip_runtime.h>
#include <hip/hip_cooperative_groups.h>

namespace cg = cooperative_groups;

#define B_   64
#define T_   512
#define DI_  512
#define H_   1024
#define G4H  4096

__device__ __forceinline__ float sigm(float x) {
    return 1.0f / (1.0f + __expf(-x));
}
__device__ __forceinline__ float tanh_fast(float x) {
    return 2.0f / (1.0f + __expf(-2.0f * x)) - 1.0f;
}

// Pack Whh into per-block slices: Wpk[bid][k][n] = Whh[(n>>2)*1024 + bid*4 + (n&3)][k]
// Block bid owns h-columns j0..j0+3 (j0 = bid*4) -> 16 gate rows (4 gates x 4 cols).
__global__ __launch_bounds__(256) void pack_whh(
    const float* __restrict__ Whh, float* __restrict__ Wpk)
{
    const int bid = blockIdx.x;
    const int j0  = bid * 4;
    const int tid = threadIdx.x;
    const int n   = tid >> 4;      // 0..15
    const int lo  = tid & 15;      // 0..15
    const int row = (n >> 2) * H_ + j0 + (n & 3);
    const float* src = Whh + (size_t)row * H_;
    float* dst = Wpk + (size_t)bid * 16384 + n;
#pragma unroll
    for (int u = 0; u < 16; ++u) {
        const int k = u * 64 + lo * 4;
        const float4 v = *(const float4*)(src + k);
        dst[(size_t)(k + 0) * 16] = v.x;
        dst[(size_t)(k + 1) * 16] = v.y;
        dst[(size_t)(k + 2) * 16] = v.z;
        dst[(size_t)(k + 3) * 16] = v.w;
    }
}

// xp[tl][b][n] = X[b][t0+tl][:] . Wih[n][:] + (bih[n]+bhh[n])   (unchanged)
__global__ __launch_bounds__(256) void xproj_gemm(
    const float* __restrict__ X, const float* __restrict__ Wih,
    const float* __restrict__ bih, const float* __restrict__ bhh,
    float* __restrict__ xp, int t0)
{
    __shared__ float As[16][64];   // [k][b]
    __shared__ float Bs[16][64];   // [k][n]
    const int tl = blockIdx.y;
    const int n0 = blockIdx.x * 64;
    const int t  = t0 + tl;
    const int tid = threadIdx.x;
    const int ab = tid >> 2;
    const int ak = (tid & 3) * 4;
    const int wn = tid >> 2;
    const int wk = (tid & 3) * 4;
    const int by = tid >> 4;
    const int nx = tid & 15;

    const float* Ap = X + ((size_t)ab * T_ + t) * DI_ + ak;
    const float* Bp = Wih + (size_t)(n0 + wn) * DI_ + wk;

    float acc[4][4] = {};

    for (int k0 = 0; k0 < DI_; k0 += 16) {
        const float4 av = *(const float4*)(Ap + k0);
        const float4 bv = *(const float4*)(Bp + k0);
        __syncthreads();
        As[ak + 0][ab] = av.x; As[ak + 1][ab] = av.y;
        As[ak + 2][ab] = av.z; As[ak + 3][ab] = av.w;
        Bs[wk + 0][wn] = bv.x; Bs[wk + 1][wn] = bv.y;
        Bs[wk + 2][wn] = bv.z; Bs[wk + 3][wn] = bv.w;
        __syncthreads();
#pragma unroll
        for (int k = 0; k < 16; ++k) {
            const float4 a4 = *(const float4*)&As[k][by * 4];
            const float4 b4 = *(const float4*)&Bs[k][nx * 4];
            const float ar[4] = {a4.x, a4.y, a4.z, a4.w};
            const float br[4] = {b4.x, b4.y, b4.z, b4.w};
#pragma unroll
            for (int i = 0; i < 4; ++i)
#pragma unroll
                for (int j = 0; j < 4; ++j)
                    acc[i][j] = fmaf(ar[i], br[j], acc[i][j]);
        }
    }

    const int nb = n0 + nx * 4;
    const float4 b1 = *(const float4*)(bih + nb);
    const float4 b2 = *(const float4*)(bhh + nb);
    const float4 bb4 = {b1.x + b2.x, b1.y + b2.y, b1.z + b2.z, b1.w + b2.w};
#pragma unroll
    for (int i = 0; i < 4; ++i) {
        const int b = by * 4 + i;
        float4 v;
        v.x = acc[i][0] + bb4.x;
        v.y = acc[i][1] + bb4.y;
        v.z = acc[i][2] + bb4.z;
        v.w = acc[i][3] + bb4.w;
        *(float4*)(xp + ((size_t)tl * B_ + b) * G4H + nb) = v;
    }
}

// Persistent cooperative recurrence kernel.
// Grid 256 blocks (1/CU), 512 threads (8 waves). Block bid owns h-cols j0..j0+3.
// KEY CHANGE vs prev round: the block's 64 KB Whh slice is preloaded into LDS ONCE.
// grid.sync()'s device-scope acquire invalidates L2 every step (8-XCD non-coherence),
// which previously re-fetched all 16 MB of Wpk from HBM per step (measured: FETCH
// 7.3 GB/dispatch = 512 x 16 MB). LDS is immune to that invalidation.
// c for the block's own 4 columns lives in registers of lanes 0..63 for the whole
// launch (loaded from / stored to global cS only at chunk boundaries).
__global__ __launch_bounds__(512) void lstm_recur(
    const float* __restrict__ Wpk, const float* __restrict__ xp,
    float* __restrict__ hT, float* __restrict__ cS,
    float* __restrict__ hs, float* __restrict__ cs,
    int t0, int clen)
{
    __shared__ float Ws[16384];        // 64 KB: resident W slice, [k][16n], stride 16
    __shared__ float Hs[2][4096];      // two 64k x 64b h tiles (double buffer)
    __shared__ float gate[64 * 21];    // [b][n], stride 21 to spread atomics
    __shared__ float hloc[256];        // [q][b] h_new staging for transposed write

    const int tid = threadIdx.x;
    const int bid = blockIdx.x;
    const int j0  = bid * 4;
    const float* Wb = Wpk + (size_t)bid * 16384;

    const int wv = tid >> 6;           // wave 0..7 -> k-subrange within tile
    const int ln = tid & 63;
    const int b4 = ln >> 2;            // 0..15 -> batches b4*4..+3
    const int n4 = ln & 3;             // 0..3  -> gate cols n4*4..+3

    // ---- one-time: W slice global -> LDS (64 KB), c slice -> registers ----
#pragma unroll
    for (int u = 0; u < 8; ++u)
        *(float4*)(&Ws[u * 2048 + tid * 4]) = *(const float4*)(Wb + u * 2048 + tid * 4);

    float creg[4] = {0.f, 0.f, 0.f, 0.f};
    if (tid < 64) {
        const float4 cv = *(const float4*)(cS + (size_t)tid * H_ + j0);
        creg[0] = cv.x; creg[1] = cv.y; creg[2] = cv.z; creg[3] = cv.w;
    }
    __syncthreads();

    cg::grid_group grid = cg::this_grid();

    for (int tl = 0; tl < clen; ++tl) {
        const int t = t0 + tl;

        // ---- stage h tile 0 (all threads); init gates with xp (lanes 0..255) ----
        {
            const float4 a0 = *(const float4*)(hT + tid * 4);
            const float4 a1 = *(const float4*)(hT + 2048 + tid * 4);
            *(float4*)(&Hs[0][tid * 4])        = a0;
            *(float4*)(&Hs[0][2048 + tid * 4]) = a1;
        }
        if (tid < 256) {
            const int b = tid >> 2, g = tid & 3;
            const float4 v = *(const float4*)(xp + ((size_t)tl * B_ + b) * G4H + g * H_ + j0);
            float* gp = gate + b * 21 + g * 4;
            gp[0] = v.x; gp[1] = v.y; gp[2] = v.z; gp[3] = v.w;
        }
        __syncthreads();

        // ---- K loop: 16 tiles of 64 k; h double-buffered; W read from resident LDS ----
        float acc[4][4] = {};
        for (int kt = 0; kt < 16; ++kt) {
            const int buf = kt & 1;
            float4 r0, r1;
            if (kt < 15) {
                const float* hsrc = hT + (kt + 1) * 4096;
                r0 = *(const float4*)(hsrc + tid * 4);
                r1 = *(const float4*)(hsrc + 2048 + tid * 4);
            }
            const float* Hb = &Hs[buf][0];
            const float* Wk = &Ws[kt * 1024];
#pragma unroll
            for (int kk = 0; kk < 8; ++kk) {
                const int k = wv * 8 + kk;
                const float4 hv = *(const float4*)(Hb + k * 64 + b4 * 4);
                const float4 wq = *(const float4*)(Wk + k * 16 + n4 * 4);
                const float hr[4] = {hv.x, hv.y, hv.z, hv.w};
                const float wr[4] = {wq.x, wq.y, wq.z, wq.w};
#pragma unroll
                for (int i = 0; i < 4; ++i)
#pragma unroll
                    for (int j = 0; j < 4; ++j)
                        acc[i][j] = fmaf(hr[i], wr[j], acc[i][j]);
            }
            if (kt < 15) {
                *(float4*)(&Hs[buf ^ 1][tid * 4])        = r0;
                *(float4*)(&Hs[buf ^ 1][2048 + tid * 4]) = r1;
                __syncthreads();
            }
        }

        // ---- cross-wave reduce into gates ----
#pragma unroll
        for (int i = 0; i < 4; ++i)
#pragma unroll
            for (int j = 0; j < 4; ++j)
                atomicAdd(&gate[(b4 * 4 + i) * 21 + n4 * 4 + j], acc[i][j]);
        __syncthreads();

        // ---- pointwise: gates -> c,h; c stays in registers; write hs, cs ----
        if (tid < 64) {
            const int b = tid;
            const float* gp = gate + b * 21;
            float cn[4], hn[4];
#pragma unroll
            for (int q = 0; q < 4; ++q) {
                const float ig = sigm(gp[q]);
                const float fg = sigm(gp[4 + q]);
                const float gg = tanh_fast(gp[8 + q]);
                const float og = sigm(gp[12 + q]);
                const float c2 = fmaf(fg, creg[q], ig * gg);
                cn[q] = c2;
                hn[q] = og * tanh_fast(c2);
                creg[q] = c2;
            }
            const float4 c4 = {cn[0], cn[1], cn[2], cn[3]};
            const float4 h4 = {hn[0], hn[1], hn[2], hn[3]};
            const size_t o = ((size_t)b * T_ + t) * H_ + j0;
            *(float4*)(hs + o) = h4;
            *(float4*)(cs + o) = c4;
            hloc[0 * 64 + b] = hn[0];
            hloc[1 * 64 + b] = hn[1];
            hloc[2 * 64 + b] = hn[2];
            hloc[3 * 64 + b] = hn[3];
        }
        __syncthreads();
        if (tid < 64) {
            const int q = tid >> 4, x = tid & 15;
            *(float4*)(hT + (j0 + q) * 64 + x * 4) = *(const float4*)(hloc + q * 64 + x * 4);
        }
        grid.sync();
    }

    // ---- persist c for next chunk ----
    if (tid < 64) {
        const float4 c4 = {creg[0], creg[1], creg[2], creg[3]};
        *(float4*)(cS + (size_t)tid * H_ + j0) = c4;
    }
}

__global__ __launch_bounds__(256) void gather_last(
    const float* __restrict__ hs, const float* __restrict__ cs,
    const int* __restrict__ length,
    float* __restrict__ hl, float* __restrict__ cl)
{
    const int i = blockIdx.x * 256 + threadIdx.x;   // B*H total
    const int b = i >> 10;
    const int j = i & 1023;
    const int tt = length[b] - 1;
    const size_t src = ((size_t)b * T_ + tt) * H_ + j;
    hl[i] = hs[src];
    cl[i] = cs[src];
}

extern "C" void kernel_launch(void* const* d_in, const int* in_sizes, int n_in,
                              void* d_out, int out_size, void* d_ws, size_t ws_size,
                              hipStream_t stream)
{
    const float* X   = (const float*)d_in[0];
    const float* Wih = (const float*)d_in[1];
    const float* Whh = (const float*)d_in[2];
    const float* bih = (const float*)d_in[3];
    const float* bhh = (const float*)d_in[4];
    const int*   len = (const int*)d_in[5];

    float* out = (float*)d_out;
    float* hs = out;
    float* cs = hs + (size_t)B_ * T_ * H_;
    float* hl = cs + (size_t)B_ * T_ * H_;
    float* cl = hl + (size_t)B_ * H_;

    // ws layout: hT (1024x64) | cS (64x1024) | Wpk (1024x4096) | xp chunk
    float* hT  = (float*)d_ws;
    float* cS  = hT + 65536;
    float* Wpk = cS + 65536;
    float* xp  = Wpk + (size_t)H_ * G4H;

    const size_t fixed_bytes = ((size_t)131072 + (size_t)H_ * G4H) * sizeof(float);
    const size_t per_t = (size_t)B_ * G4H * sizeof(float);   // 1 MiB per timestep

    int Tc = 1;
    if (ws_size > fixed_bytes + per_t) {
        size_t m = (ws_size - fixed_bytes) / per_t;
        Tc = (int)(m > (size_t)T_ ? (size_t)T_ : m);
    }

    hipMemsetAsync(hT, 0, (size_t)131072 * sizeof(float), stream);   // hT + cS
    pack_whh<<<256, 256, 0, stream>>>(Whh, Wpk);

    for (int t0 = 0; t0 < T_; t0 += Tc) {
        const int clen = (T_ - t0 < Tc) ? (T_ - t0) : Tc;
        xproj_gemm<<<dim3(G4H / 64, clen), 256, 0, stream>>>(X, Wih, bih, bhh, xp, t0);
        int t0a = t0, cla = clen;
        void* args[] = {(void*)&Wpk, (void*)&xp, (void*)&hT, (void*)&cS,
                        (void*)&hs, (void*)&cs, (void*)&t0a, (void*)&cla};
        hipLaunchCooperativeKernel((const void*)lstm_recur, dim3(256), dim3(512),
                                   args, 0, stream);
    }

    gather_last<<<(B_ * H_) / 256, 256, 0, stream>>>(hs, cs, len, hl, cl);
}